// Round 3
// baseline (1053.176 us; speedup 1.0000x reference)
//
#include <hip/hip_runtime.h>

// NSGT sliced arrange(fwd): per-band circular left-shift along last axis.
//   out[s,c,b,m] = in[s,c,b,(m + mid(s)) % M],  mid = 3M/4 (s even), M/4 (s odd)
// Pure permutation -> memory-bound. All mids are multiples of 256 elements, so
// we operate in float4 (16B) units: rotate by mid/4 vec-lanes within each row.
// All dims are powers of two -> shift/mask arithmetic only.
//
// Single fused kernel for all 4 bands (band boundaries are multiples of the
// 256-thread block, so each block is band-uniform; compile-time constants per
// band via template dispatch).

template <int LOG2_MVEC, int LOG2_RPS, int EVEN_MID_VEC, int ODD_MID_VEC>
__device__ __forceinline__ void shift_one(const float4* __restrict__ in,
                                          float4* __restrict__ out, int v) {
    constexpr int mvec_mask = (1 << LOG2_MVEC) - 1;
    int lane = v & mvec_mask;             // vec4 position within row
    int s    = v >> (LOG2_MVEC + LOG2_RPS);
    int mid  = (s & 1) ? ODD_MID_VEC : EVEN_MID_VEC;
    int src_lane = (lane + mid) & mvec_mask;
    out[v] = in[(v - lane) + src_lane];
}

// Band shapes: (128,2,32,1024) (128,2,64,2048) (128,2,64,4096) (128,2,32,8192)
// vec4 counts:   2,097,152       8,388,608      16,777,216      16,777,216
#define C0 2097152
#define C1 10485760
#define C2 27262976
#define C3 44040192

__global__ __launch_bounds__(256) void band_shift_fused(
    const float4* __restrict__ in0, const float4* __restrict__ in1,
    const float4* __restrict__ in2, const float4* __restrict__ in3,
    float4* __restrict__ out)
{
    int v = blockIdx.x * 256 + threadIdx.x;
    if (v < C0) {
        // M=1024: mvec=256 (log2=8), rps=64 (log2=6), mids: even 192, odd 64
        shift_one<8, 6, 192, 64>(in0, out, v);
    } else if (v < C1) {
        // M=2048: mvec=512 (9), rps=128 (7), mids: even 384, odd 128
        shift_one<9, 7, 384, 128>(in1, out + C0, v - C0);
    } else if (v < C2) {
        // M=4096: mvec=1024 (10), rps=128 (7), mids: even 768, odd 256
        shift_one<10, 7, 768, 256>(in2, out + C1, v - C1);
    } else {
        // M=8192: mvec=2048 (11), rps=64 (6), mids: even 1536, odd 512
        shift_one<11, 6, 1536, 512>(in3, out + C2, v - C2);
    }
}

extern "C" void kernel_launch(void* const* d_in, const int* in_sizes, int n_in,
                              void* d_out, int out_size, void* d_ws, size_t ws_size,
                              hipStream_t stream) {
    const int block = 256;
    const int grid = C3 / block;  // 172,032 blocks, exact
    band_shift_fused<<<grid, block, 0, stream>>>(
        (const float4*)d_in[0], (const float4*)d_in[1],
        (const float4*)d_in[2], (const float4*)d_in[3],
        (float4*)d_out);
}